// Round 2
// baseline (1315.718 us; speedup 1.0000x reference)
//
#include <hip/hip_runtime.h>
#include <stdint.h>

#define B_   2
#define T_   512
#define E_   256
#define H_   256
#define VOC  32000
#define G4   1024   // 4*H

#define SENT 0x7f800001u   // signaling-NaN sentinel; |h|<1 so never a legit h bit pattern

// ---- workspace layout (bytes, 256-aligned) ----
#define OFF_GX    0u                   // 2*512*1024 f32            = 4,194,304
#define OFF_H     4194304u             // 513*2*256 f32 (h ladder)  = 1,050,624
#define OFF_PROJ  5244928u             // 1024*512 f32 (a||b proj)  = 2,097,152
#define OFF_SCORE 7342080u             // 2*512*512 f32             = 2,097,152
#define OFF_ABF   9439232u             // 1024*512 bf16 (combined)  = 1,048,576
#define OFF_WBF   10487808u            // 32000*512 bf16            = 32,768,000
// total = 43,255,808 bytes

typedef __attribute__((ext_vector_type(8))) short short8;
typedef __attribute__((ext_vector_type(4))) float f32x4;

__device__ __forceinline__ unsigned short f2bf(float f) {
    unsigned u = __float_as_uint(f);
    unsigned r = (u + 0x7FFFu + ((u >> 16) & 1u)) >> 16;   // RNE
    return (unsigned short)r;
}
__device__ __forceinline__ float sigmoid_f(float x) {
    return 1.0f / (1.0f + __expf(-x));
}
__device__ __forceinline__ float tanh_f(float x) {
    float e = __expf(-2.0f * fabsf(x));
    float t = (1.0f - e) / (1.0f + e);
    return (x >= 0.0f) ? t : -t;
}

// ---------------- init: h[0]=0, h[1..512]=sentinel ----------------
__global__ __launch_bounds__(256) void k_init(unsigned* hbuf) {
    int idx = blockIdx.x * 256 + threadIdx.x;
    if (idx < 513 * 2 * 256) hbuf[idx] = (idx < 2 * 256) ? 0u : SENT;
}

// ---------------- embed gather + gx = xe@W_ih^T + b_ih + b_hh ----------------
// C[m][n], m=b*512+t (1024), n=gate row (1024), K=256.  64x64 tiles, 4x4/thread.
__global__ __launch_bounds__(256) void k_embed_gx(const int* __restrict__ x,
                                                  const float* __restrict__ emb,
                                                  const float* __restrict__ Wih,
                                                  const float* __restrict__ bih,
                                                  const float* __restrict__ bhh,
                                                  float* __restrict__ gx) {
    __shared__ float As[64 * 65];
    __shared__ float Bs[64 * 65];
    int t = threadIdx.x;
    int n0 = blockIdx.x * 64, m0 = blockIdx.y * 64;
    int ty = t >> 4, tx = t & 15;
    float c[4][4] = {};
    for (int kc = 0; kc < E_; kc += 64) {
        __syncthreads();
        #pragma unroll
        for (int i = 0; i < 4; ++i) {
            int f = i * 256 + t;
            int r = f >> 4, c4 = f & 15;
            int xi = x[m0 + r];
            float4 av = *(const float4*)(emb + (size_t)xi * E_ + kc + c4 * 4);
            As[r * 65 + c4 * 4 + 0] = av.x; As[r * 65 + c4 * 4 + 1] = av.y;
            As[r * 65 + c4 * 4 + 2] = av.z; As[r * 65 + c4 * 4 + 3] = av.w;
            float4 bv = *(const float4*)(Wih + (size_t)(n0 + r) * E_ + kc + c4 * 4);
            Bs[r * 65 + c4 * 4 + 0] = bv.x; Bs[r * 65 + c4 * 4 + 1] = bv.y;
            Bs[r * 65 + c4 * 4 + 2] = bv.z; Bs[r * 65 + c4 * 4 + 3] = bv.w;
        }
        __syncthreads();
        for (int k = 0; k < 64; ++k) {
            float a[4], b[4];
            #pragma unroll
            for (int ii = 0; ii < 4; ++ii) a[ii] = As[(ty * 4 + ii) * 65 + k];
            #pragma unroll
            for (int jj = 0; jj < 4; ++jj) b[jj] = Bs[(tx * 4 + jj) * 65 + k];
            #pragma unroll
            for (int ii = 0; ii < 4; ++ii)
                #pragma unroll
                for (int jj = 0; jj < 4; ++jj)
                    c[ii][jj] = fmaf(a[ii], b[jj], c[ii][jj]);
        }
    }
    #pragma unroll
    for (int ii = 0; ii < 4; ++ii)
        #pragma unroll
        for (int jj = 0; jj < 4; ++jj) {
            int m = m0 + ty * 4 + ii, n = n0 + tx * 4 + jj;
            gx[(size_t)m * G4 + n] = c[ii][jj] + bih[n] + bhh[n];
        }
}

// ---------------- LSTM scan (8 worker blocks) + Wfc->bf16 convert (24 blocks) --------
// Workers: bid%8 in {0,1} = batch; bid/8 = quarter (64 units, 256 gate rows).
// bid%8 round-robins XCDs, so {0,8,16,24} (batch0) share XCD0's L2 (perf-only heuristic).
// Thread t: gate-row rl=t>>1, half=t&1 holds 128 fp32 W_hh weights in VGPRs.
// Cross-block handoff: value-polling on sentinel (relaxed agent atomics, per-step buffers).
__global__ __launch_bounds__(512) void k_lstm(const float* __restrict__ Whh,
                                              const float* __restrict__ gx,
                                              float* hbuf,
                                              const float* __restrict__ Wfc,
                                              unsigned short* __restrict__ Wbf) {
    int bid = blockIdx.x;
    int role = bid & 7;
    int t = threadIdx.x;
    if (role >= 2) {                       // ---- converter role ----
        int c = (bid >> 3) * 6 + role - 2; // 0..23
        const float4* src = (const float4*)Wfc;
        ushort4* dst = (ushort4*)Wbf;
        for (int idx = c * 512 + t; idx < VOC * 512 / 4; idx += 24 * 512) {
            float4 v = src[idx];
            ushort4 o;
            o.x = f2bf(v.x); o.y = f2bf(v.y); o.z = f2bf(v.z); o.w = f2bf(v.w);
            dst[idx] = o;
        }
        return;
    }
    int beta = role;         // batch
    int q = bid >> 3;        // quarter
    __shared__ float hs[256];
    __shared__ float p[256];
    int rl = t >> 1, half = t & 1;
    int g = rl >> 6, u = rl & 63;
    int row = g * 256 + q * 64 + u;        // W_hh row (PyTorch i,f,g,o order)
    float w[128];
    #pragma unroll
    for (int k = 0; k < 32; ++k) {
        float4 wv = *(const float4*)(Whh + (size_t)row * 256 + half * 128 + k * 4);
        w[k * 4 + 0] = wv.x; w[k * 4 + 1] = wv.y; w[k * 4 + 2] = wv.z; w[k * 4 + 3] = wv.w;
    }
    float c_reg = 0.0f;
    const float* gxb = gx + (size_t)beta * T_ * G4;
    unsigned* hb = (unsigned*)hbuf;
    for (int s = 0; s < T_; ++s) {
        float gxv = (half == 0) ? gxb[(size_t)s * G4 + row] : 0.0f;  // prefetch early
        if (t < 256) {
            unsigned* pp = hb + (s * 2 + beta) * 256 + t;
            unsigned v;
            do {
                v = __hip_atomic_load(pp, __ATOMIC_RELAXED, __HIP_MEMORY_SCOPE_AGENT);
            } while (v == SENT);
            hs[t] = __uint_as_float(v);
        }
        __syncthreads();
        float acc = gxv;
        #pragma unroll
        for (int kk = 0; kk < 32; ++kk) {
            float4 h4 = *(const float4*)(hs + half * 128 + kk * 4);  // LDS broadcast
            acc = fmaf(w[kk * 4 + 0], h4.x, acc);
            acc = fmaf(w[kk * 4 + 1], h4.y, acc);
            acc = fmaf(w[kk * 4 + 2], h4.z, acc);
            acc = fmaf(w[kk * 4 + 3], h4.w, acc);
        }
        acc += __shfl_xor(acc, 1);         // combine the two K-halves
        if (half == 0) p[rl] = acc;
        __syncthreads();
        if (t < 64) {
            float pi = p[t], pf = p[64 + t], pg = p[128 + t], po = p[192 + t];
            float ig = sigmoid_f(pi), fg = sigmoid_f(pf);
            float gg = tanh_f(pg),    og = sigmoid_f(po);
            c_reg = fmaf(fg, c_reg, ig * gg);
            float h = og * tanh_f(c_reg);
            __hip_atomic_store(hb + ((s + 1) * 2 + beta) * 256 + q * 64 + t,
                               __float_as_uint(h),
                               __ATOMIC_RELAXED, __HIP_MEMORY_SCOPE_AGENT);
        }
    }
}

// ---------------- a/b projections: proj[m][0:256]=out@W1^T+b1, [256:512]=out@W2^T+b2 ----
__global__ __launch_bounds__(256) void k_proj(const float* __restrict__ hbuf,
                                              const float* __restrict__ W1,
                                              const float* __restrict__ b1,
                                              const float* __restrict__ W2,
                                              const float* __restrict__ b2,
                                              float* __restrict__ proj) {
    __shared__ float As[64 * 65];
    __shared__ float Bs[64 * 65];
    int t = threadIdx.x;
    int n0 = blockIdx.x * 64, m0 = blockIdx.y * 64;
    int ty = t >> 4, tx = t & 15;
    float c[4][4] = {};
    for (int kc = 0; kc < H_; kc += 64) {
        __syncthreads();
        #pragma unroll
        for (int i = 0; i < 4; ++i) {
            int f = i * 256 + t;
            int r = f >> 4, c4 = f & 15;
            int m = m0 + r; int bb = m >> 9, tl = m & 511;
            float4 av = *(const float4*)(hbuf + ((size_t)(tl + 1) * 2 + bb) * H_ + kc + c4 * 4);
            As[r * 65 + c4 * 4 + 0] = av.x; As[r * 65 + c4 * 4 + 1] = av.y;
            As[r * 65 + c4 * 4 + 2] = av.z; As[r * 65 + c4 * 4 + 3] = av.w;
            int n = n0 + r;
            const float* Wp = (n < 256) ? (W1 + (size_t)n * H_) : (W2 + (size_t)(n - 256) * H_);
            float4 bv = *(const float4*)(Wp + kc + c4 * 4);
            Bs[r * 65 + c4 * 4 + 0] = bv.x; Bs[r * 65 + c4 * 4 + 1] = bv.y;
            Bs[r * 65 + c4 * 4 + 2] = bv.z; Bs[r * 65 + c4 * 4 + 3] = bv.w;
        }
        __syncthreads();
        for (int k = 0; k < 64; ++k) {
            float a[4], b[4];
            #pragma unroll
            for (int ii = 0; ii < 4; ++ii) a[ii] = As[(ty * 4 + ii) * 65 + k];
            #pragma unroll
            for (int jj = 0; jj < 4; ++jj) b[jj] = Bs[(tx * 4 + jj) * 65 + k];
            #pragma unroll
            for (int ii = 0; ii < 4; ++ii)
                #pragma unroll
                for (int jj = 0; jj < 4; ++jj)
                    c[ii][jj] = fmaf(a[ii], b[jj], c[ii][jj]);
        }
    }
    #pragma unroll
    for (int ii = 0; ii < 4; ++ii)
        #pragma unroll
        for (int jj = 0; jj < 4; ++jj) {
            int m = m0 + ty * 4 + ii, n = n0 + tx * 4 + jj;
            float bias = (n < 256) ? b1[n] : b2[n - 256];
            proj[(size_t)m * 512 + n] = c[ii][jj] + bias;
        }
}

// ---------------- scores: V . tanh(a_i + b_j) + bV, causal 16x16 tiles ----------------
__global__ __launch_bounds__(256) void k_scores(const float* __restrict__ proj,
                                                const float* __restrict__ V,
                                                const float* __restrict__ bV,
                                                float* __restrict__ score) {
    int jt = blockIdx.x, it = blockIdx.y, b = blockIdx.z;
    if (jt > it) return;
    __shared__ float aT[16 * 260];
    __shared__ float bT[16 * 260];
    __shared__ float Vs[256];
    int t = threadIdx.x;
    int i0 = it * 16, j0 = jt * 16;
    #pragma unroll
    for (int i = 0; i < 4; ++i) {
        int f = i * 256 + t;
        int r = f >> 6, c4 = f & 63;
        *(float4*)(aT + r * 260 + c4 * 4) =
            *(const float4*)(proj + (size_t)(b * 512 + i0 + r) * 512 + c4 * 4);
        *(float4*)(bT + r * 260 + c4 * 4) =
            *(const float4*)(proj + (size_t)(b * 512 + j0 + r) * 512 + 256 + c4 * 4);
    }
    Vs[t] = V[t];
    __syncthreads();
    int ti = t >> 4, tj = t & 15;
    float sc = 0.0f;
    #pragma unroll 4
    for (int c4 = 0; c4 < 64; ++c4) {
        float4 av = *(const float4*)(aT + ti * 260 + c4 * 4);
        float4 bv = *(const float4*)(bT + tj * 260 + c4 * 4);
        float4 vv = *(const float4*)(Vs + c4 * 4);
        sc = fmaf(vv.x, tanh_f(av.x + bv.x), sc);
        sc = fmaf(vv.y, tanh_f(av.y + bv.y), sc);
        sc = fmaf(vv.z, tanh_f(av.z + bv.z), sc);
        sc = fmaf(vv.w, tanh_f(av.w + bv.w), sc);
    }
    score[(size_t)(b * 512 + i0 + ti) * 512 + j0 + tj] = sc + bV[0];
}

// ---------------- causal softmax + context + combined(bf16) ----------------
__global__ __launch_bounds__(256) void k_softctx(const float* __restrict__ hbuf,
                                                 const float* __restrict__ score,
                                                 unsigned short* __restrict__ Abf) {
    int i = blockIdx.x, b = blockIdx.y;
    int t = threadIdx.x;
    __shared__ float pe[512];
    __shared__ float r1[4];
    __shared__ float r2[4];
    const float* srow = score + (size_t)(b * 512 + i) * 512;
    float s1 = (t <= i) ? srow[t] : -1e30f;
    float s2 = (t + 256 <= i) ? srow[t + 256] : -1e30f;
    float mx = fmaxf(s1, s2);
    for (int off = 32; off; off >>= 1) mx = fmaxf(mx, __shfl_xor(mx, off));
    int wid = t >> 6, lane = t & 63;
    if (lane == 0) r1[wid] = mx;
    __syncthreads();
    mx = fmaxf(fmaxf(r1[0], r1[1]), fmaxf(r1[2], r1[3]));
    float e1 = (t <= i) ? __expf(s1 - mx) : 0.0f;
    float e2 = (t + 256 <= i) ? __expf(s2 - mx) : 0.0f;
    pe[t] = e1; pe[t + 256] = e2;
    float sm = e1 + e2;
    for (int off = 32; off; off >>= 1) sm += __shfl_xor(sm, off);
    if (lane == 0) r2[wid] = sm;
    __syncthreads();                       // also makes pe[] visible
    sm = r2[0] + r2[1] + r2[2] + r2[3];
    float inv = 1.0f / sm;
    float acc = 0.0f;
    int n = i + 1;
    #pragma unroll 4
    for (int j = 0; j < n; ++j)            // outputs[b][j][t], coalesced in t
        acc = fmaf(pe[j], hbuf[(size_t)(j + 1) * 512 + b * 256 + t], acc);
    float ctx = acc * inv;
    float outv = hbuf[(size_t)(i + 1) * 512 + b * 256 + t];
    size_t m = (size_t)b * 512 + i;
    Abf[m * 512 + t]       = f2bf(outv);
    Abf[m * 512 + 256 + t] = f2bf(ctx);
}

// ---------------- FC: logits = combined @ Wfc^T + bfc (bf16 MFMA, 128x128 tiles) -------
__global__ __launch_bounds__(256) void k_fc(const unsigned short* __restrict__ Abf,
                                            const unsigned short* __restrict__ Wbf,
                                            const float* __restrict__ bfc,
                                            float* __restrict__ out) {
    __shared__ uint4 AsV[1024];   // 128 rows x 64 bf16 (XOR-swizzled)
    __shared__ uint4 BsV[1024];
    char* As = (char*)AsV;
    char* Bs = (char*)BsV;
    int t = threadIdx.x;
    int n0 = blockIdx.x * 128, m0 = blockIdx.y * 128;
    int wid = t >> 6, lane = t & 63;
    int wr = wid >> 1, wc = wid & 1;
    f32x4 acc[4][4];
    #pragma unroll
    for (int a = 0; a < 4; ++a)
        #pragma unroll
        for (int bq = 0; bq < 4; ++bq)
            #pragma unroll
            for (int r = 0; r < 4; ++r) acc[a][bq][r] = 0.0f;

    uint4 ra[4], rb[4];
    auto loadk = [&](int kt) {
        #pragma unroll
        for (int i = 0; i < 4; ++i) {
            int chunk = i * 256 + t, row = chunk >> 3, c8 = chunk & 7;
            ra[i] = *(const uint4*)(Abf + (size_t)(m0 + row) * 512 + kt * 64 + c8 * 8);
            rb[i] = *(const uint4*)(Wbf + (size_t)(n0 + row) * 512 + kt * 64 + c8 * 8);
        }
    };
    loadk(0);
    for (int kt = 0; kt < 8; ++kt) {
        __syncthreads();
        #pragma unroll
        for (int i = 0; i < 4; ++i) {
            int chunk = i * 256 + t, row = chunk >> 3, c8 = chunk & 7;
            int db = row * 128 + ((c8 ^ (row & 7)) << 4);   // XOR swizzle (write side)
            *(uint4*)(As + db) = ra[i];
            *(uint4*)(Bs + db) = rb[i];
        }
        __syncthreads();
        if (kt < 7) loadk(kt + 1);                          // prefetch under compute
        #pragma unroll
        for (int kk = 0; kk < 2; ++kk) {
            short8 av[4], bv[4];
            #pragma unroll
            for (int mi = 0; mi < 4; ++mi) {
                int rowl = wr * 64 + mi * 16 + (lane & 15);
                int c8 = kk * 4 + (lane >> 4);
                av[mi] = *(const short8*)(As + rowl * 128 + ((c8 ^ (rowl & 7)) << 4));
            }
            #pragma unroll
            for (int ni = 0; ni < 4; ++ni) {
                int rowl = wc * 64 + ni * 16 + (lane & 15);
                int c8 = kk * 4 + (lane >> 4);
                bv[ni] = *(const short8*)(Bs + rowl * 128 + ((c8 ^ (rowl & 7)) << 4));
            }
            #pragma unroll
            for (int mi = 0; mi < 4; ++mi)
                #pragma unroll
                for (int ni = 0; ni < 4; ++ni)
                    acc[mi][ni] = __builtin_amdgcn_mfma_f32_16x16x32_bf16(
                        av[mi], bv[ni], acc[mi][ni], 0, 0, 0);
        }
    }
    #pragma unroll
    for (int ni = 0; ni < 4; ++ni) {
        int col = n0 + wc * 64 + ni * 16 + (lane & 15);
        float bias = bfc[col];
        #pragma unroll
        for (int mi = 0; mi < 4; ++mi) {
            int rowb = m0 + wr * 64 + mi * 16 + ((lane >> 4) << 2);
            #pragma unroll
            for (int r = 0; r < 4; ++r)
                out[(size_t)(rowb + r) * VOC + col] = acc[mi][ni][r] + bias;
        }
    }
}

extern "C" void kernel_launch(void* const* d_in, const int* in_sizes, int n_in,
                              void* d_out, int out_size, void* d_ws, size_t ws_size,
                              hipStream_t stream) {
    const int*   x   = (const int*)  d_in[0];
    const float* emb = (const float*)d_in[1];
    const float* Wih = (const float*)d_in[2];
    const float* Whh = (const float*)d_in[3];
    const float* bih = (const float*)d_in[4];
    const float* bhh = (const float*)d_in[5];
    const float* W1  = (const float*)d_in[6];
    const float* b1  = (const float*)d_in[7];
    const float* W2  = (const float*)d_in[8];
    const float* b2  = (const float*)d_in[9];
    const float* V   = (const float*)d_in[10];
    const float* bV  = (const float*)d_in[11];
    const float* Wfc = (const float*)d_in[12];
    const float* bfc = (const float*)d_in[13];
    float* out = (float*)d_out;

    char* ws = (char*)d_ws;
    float* gx            = (float*)(ws + OFF_GX);
    float* hbuf          = (float*)(ws + OFF_H);
    float* proj          = (float*)(ws + OFF_PROJ);
    float* score         = (float*)(ws + OFF_SCORE);
    unsigned short* Abf  = (unsigned short*)(ws + OFF_ABF);
    unsigned short* Wbf  = (unsigned short*)(ws + OFF_WBF);

    k_init    <<<dim3(1026),       dim3(256), 0, stream>>>((unsigned*)hbuf);
    k_embed_gx<<<dim3(16, 16),     dim3(256), 0, stream>>>(x, emb, Wih, bih, bhh, gx);
    k_lstm    <<<dim3(32),         dim3(512), 0, stream>>>(Whh, gx, hbuf, Wfc, Wbf);
    k_proj    <<<dim3(8, 16),      dim3(256), 0, stream>>>(hbuf, W1, b1, W2, b2, proj);
    k_scores  <<<dim3(32, 32, 2),  dim3(256), 0, stream>>>(proj, V, bV, score);
    k_softctx <<<dim3(512, 2),     dim3(256), 0, stream>>>(hbuf, score, Abf);
    k_fc      <<<dim3(250, 8),     dim3(256), 0, stream>>>(Abf, Wbf, bfc, out);
}